// Round 7
// baseline (203.529 us; speedup 1.0000x reference)
//
#include <hip/hip_runtime.h>
#include <hip/hip_bf16.h>

#define NROWS 16384
#define DIM 128
#define TAU_INV 14.285714285714285714f
#define K1_CONST 20.6099273650808706f /* log2(e)/tau ; exp(cos/tau) = 2^(K1*cos) */

typedef __attribute__((ext_vector_type(8))) __bf16 bf16x8;
typedef __attribute__((ext_vector_type(16))) float f32x16;
typedef unsigned int u32;
typedef unsigned short u16;

#if __has_builtin(__builtin_amdgcn_exp2f)
#define EXP2F(x) __builtin_amdgcn_exp2f(x)
#else
#define EXP2F(x) exp2f(x)
#endif

__device__ __forceinline__ u16 f2bf(float x) {
  __hip_bfloat16 h = __float2bfloat16(x);
  return *reinterpret_cast<u16*>(&h);
}

__device__ __forceinline__ void gload_lds16(const void* g, void* l) {
  __builtin_amdgcn_global_load_lds(
      (const __attribute__((address_space(1))) u32*)g,
      (__attribute__((address_space(3))) u32*)l, 16, 0, 0);
}

// ------- Kernel A: normalize -> z1q (K1-scaled Q), z1c/z2c (unit), pos -----
__global__ __launch_bounds__(256) void nrm_kernel(
    const float* __restrict__ z1, const float* __restrict__ z2,
    u16* __restrict__ z1q, u16* __restrict__ z1c, u16* __restrict__ z2c,
    float* __restrict__ pos_sim)
{
  const int tid  = threadIdx.x;
  const int lane = tid & 63, wid = tid >> 6;
  const int row  = blockIdx.x * 4 + wid;
  const float2 a = *(const float2*)(z1 + (size_t)row * DIM + lane * 2);
  const float2 b = *(const float2*)(z2 + (size_t)row * DIM + lane * 2);
  float ss1 = a.x * a.x + a.y * a.y;
  float ss2 = b.x * b.x + b.y * b.y;
  float dd  = a.x * b.x + a.y * b.y;
#pragma unroll
  for (int d = 1; d < 64; d <<= 1) {
    ss1 += __shfl_xor(ss1, d);
    ss2 += __shfl_xor(ss2, d);
    dd  += __shfl_xor(dd,  d);
  }
  const float inv1 = 1.0f / fmaxf(sqrtf(ss1), 1e-12f);
  const float inv2 = 1.0f / fmaxf(sqrtf(ss2), 1e-12f);
  const float s1q = inv1 * K1_CONST;
  u32 pq = (u32)f2bf(a.x * s1q) | ((u32)f2bf(a.y * s1q) << 16);
  u32 p1 = (u32)f2bf(a.x * inv1) | ((u32)f2bf(a.y * inv1) << 16);
  u32 p2 = (u32)f2bf(b.x * inv2) | ((u32)f2bf(b.y * inv2) << 16);
  ((u32*)z1q)[(size_t)row * (DIM / 2) + lane] = pq;
  ((u32*)z1c)[(size_t)row * (DIM / 2) + lane] = p1;
  ((u32*)z2c)[(size_t)row * (DIM / 2) + lane] = p2;
  if (lane == 0) pos_sim[row] = dd * inv1 * inv2 * TAU_INV;
}

// ---------------- Kernel B: fused GEMM + sum(2^score), 32x32x16 ------------
// grid = 1024 : rb = bx&63 (256 q-rows), ch = bx>>6 (16 chunks of 2048 cols)
// ch<8 -> z2c (cross view), ch>=8 -> z1c (intra, diag masked)
// 4 waves/block, each wave: 64 q-rows (2 groups of 32), 64 cols/tile.
// 32x32x16 MFMA: 32/tile @2382TF vs 64 16x16x32 @2075TF (-18% mfma issue).
// exp sums accumulate pairwise into float2 -> v_pk_add_f32 (half add issue).
__global__ __launch_bounds__(256, 2) void lse_kernel(
    const u16* __restrict__ z1q, const u16* __restrict__ z1c,
    const u16* __restrict__ z2c, float* __restrict__ lparts)
{
  __shared__ __attribute__((aligned(16))) char smem[49152]; // 3 x 64x128 bf16
  const int tid    = threadIdx.x;
  const int lane   = tid & 63, wid = tid >> 6;
  const int rb     = blockIdx.x & 63, ch = blockIdx.x >> 6;
  const int lane31 = lane & 31, laneHi = lane >> 5, lane15 = lane & 15;
  const int qb     = rb * 256 + wid * 64; // this wave's first q-row

  // Q fragments (B-operand of 32x32x16): lane holds B[k=laneHi*8+i][col=lane31]
  // col = q-row (qb + qg2*32 + lane31); k-offset = ks*16 + laneHi*8, 8 bf16
  bf16x8 qf[2][8];
#pragma unroll
  for (int qg2 = 0; qg2 < 2; ++qg2)
#pragma unroll
    for (int ks = 0; ks < 8; ++ks)
      qf[qg2][ks] = *(const bf16x8*)(z1q +
          (size_t)(qb + qg2 * 32 + lane31) * DIM + ks * 16 + laneHi * 8);

  // column source for this chunk (wave-uniform constant)
  const u16* zt = (ch < 8) ? (z2c + (size_t)ch * 2048 * DIM)
                           : (z1c + (size_t)(ch - 8) * 2048 * DIM);
  int t_diag = -1;
  if (ch >= 8) {
    const int dbase = qb - (ch - 8) * 2048;
    if (dbase >= 0 && dbase < 2048) t_diag = dbase >> 6;
  }

  // staging: LDS linear, global source pre-swizzled with 4-bit row rotation
  // LDS[r][c] = G[r][c ^ (r&15)] (16B chunks)
  const int gchunk = (tid & 15) ^ ((tid >> 4) & 15);
  const char* const src0 = (const char*)zt + (((tid >> 4) << 8) + (gchunk << 4));
  char* const dst0 = smem + (wid << 10);

  // A-frag read offsets: row = cb*32 + lane31, G-chunk g = 2*ks + laneHi,
  // LDS chunk = g ^ (row&15). cb*8192 + bufo fold into ds_read immediate.
  int aoff[8];
#pragma unroll
  for (int ks = 0; ks < 8; ++ks)
    aoff[ks] = lane31 * 256 + ((((ks << 1) + laneHi) ^ lane15) << 4);

  float2 lacc0 = {0.f, 0.f}, lacc1 = {0.f, 0.f};

  auto stage_chunk = [&](int t, int i) { // tile t, quarter i -> buf (t%3)
    gload_lds16(src0 + (size_t)t * 16384 + (i << 12),
                dst0 + (t % 3) * 16384 + (i << 12));
  };

  // sum exps of one 32x32 D block into s (pairwise -> v_pk_add_f32)
  auto sumexp = [&](const f32x16& d, float2& s, bool domask) {
    if (!domask) {
#pragma unroll
      for (int r = 0; r < 16; r += 2) {
        float2 t2;
        t2.x = EXP2F(d[r]);
        t2.y = EXP2F(d[r + 1]);
        s += t2;
      }
    } else {
#pragma unroll
      for (int r = 0; r < 16; r += 2) {
        float e0 = EXP2F(d[r]);
        float e1 = EXP2F(d[r + 1]);
        // D row-in-block i = (r&3) + 8*(r>>2) + 4*laneHi ; mask i == lane31
        if (lane31 == ((r & 3) + 8 * (r >> 2) + 4 * laneHi)) e0 = 0.f;
        if (lane31 == (((r + 1) & 3) + 8 * ((r + 1) >> 2) + 4 * laneHi)) e1 = 0.f;
        float2 t2; t2.x = e0; t2.y = e1;
        s += t2;
      }
    }
  };

  auto tile = [&](int t, int bufo, bool dtile, bool pre) {
#pragma unroll
    for (int cb = 0; cb < 2; ++cb) {
      if (pre) stage_chunk(t + 2, cb * 2);
      bf16x8 af[8];
#pragma unroll
      for (int ks = 0; ks < 8; ++ks)
        af[ks] = *(const bf16x8*)(smem + bufo + cb * 8192 + aoff[ks]);
      if (pre) stage_chunk(t + 2, cb * 2 + 1);
      __builtin_amdgcn_s_setprio(1);
      f32x16 a0 = __builtin_amdgcn_mfma_f32_32x32x16_bf16(
          af[0], qf[0][0], (f32x16)(0.0f), 0, 0, 0);
      f32x16 a1 = __builtin_amdgcn_mfma_f32_32x32x16_bf16(
          af[0], qf[1][0], (f32x16)(0.0f), 0, 0, 0);
#pragma unroll
      for (int ks = 1; ks < 8; ++ks) {
        a0 = __builtin_amdgcn_mfma_f32_32x32x16_bf16(af[ks], qf[0][ks], a0, 0, 0, 0);
        a1 = __builtin_amdgcn_mfma_f32_32x32x16_bf16(af[ks], qf[1][ks], a1, 0, 0, 0);
      }
      __builtin_amdgcn_s_setprio(0);
      sumexp(a0, lacc0, dtile && (cb == 0));
      sumexp(a1, lacc1, dtile && (cb == 1));
    }
  };

  // prologue: stage tiles 0 and 1; wait tile 0 only (vmcnt(4) = allow tile 1)
#pragma unroll
  for (int i = 0; i < 4; ++i) stage_chunk(0, i);
#pragma unroll
  for (int i = 0; i < 4; ++i) stage_chunk(1, i);
  asm volatile("s_waitcnt vmcnt(4)" ::: "memory");
  __builtin_amdgcn_s_barrier();
  __builtin_amdgcn_sched_barrier(0);

#pragma unroll 1
  for (int t = 0; t < 32; ++t) {
    tile(t, (t % 3) * 16384, t == t_diag, t + 2 < 32);
    // counted sync: t+1's loads (issued at t-1) forced done; t+2's may fly
    if (t < 30) asm volatile("s_waitcnt vmcnt(4)" ::: "memory");
    else        asm volatile("s_waitcnt vmcnt(0)" ::: "memory");
    if (t < 31) __builtin_amdgcn_s_barrier();
    __builtin_amdgcn_sched_barrier(0);
  }

  // lane l and l+32 hold complementary halves of the same q-row's col sums
  float s0 = lacc0.x + lacc0.y;
  float s1 = lacc1.x + lacc1.y;
  s0 += __shfl_xor(s0, 32);
  s1 += __shfl_xor(s1, 32);
  if (lane < 32) {
    lparts[(size_t)ch * NROWS + qb + lane31] = s0;
    lparts[(size_t)ch * NROWS + qb + 32 + lane31] = s1;
  }
}

// ---------------- Kernel C: finalize (32 blocks, atomic into out) ----------
// P_i = sum 2^(K1*cos) = sum exp(s_i) exactly -> lse = ln(P_i), no bias term
__global__ __launch_bounds__(256) void fin_kernel(
    const float* __restrict__ lparts, const float* __restrict__ pos,
    float* __restrict__ out)
{
  __shared__ float red[4];
  const int tid = threadIdx.x, bx = blockIdx.x;
  float s = 0.f;
#pragma unroll 1
  for (int i = bx * 512 + tid; i < (bx + 1) * 512; i += 256) {
    float l = 0.f;
#pragma unroll
    for (int c = 0; c < 16; ++c) l += lparts[(size_t)c * NROWS + i];
    s += logf(l) - pos[i];
  }
#pragma unroll
  for (int d = 1; d < 64; d <<= 1) s += __shfl_xor(s, d);
  if ((tid & 63) == 0) red[tid >> 6] = s;
  __syncthreads();
  if (tid == 0) {
    float t = (red[0] + red[1]) + (red[2] + red[3]);
    atomicAdd(out, t / (float)NROWS);
  }
}

extern "C" void kernel_launch(void* const* d_in, const int* in_sizes, int n_in,
                              void* d_out, int out_size, void* d_ws, size_t ws_size,
                              hipStream_t stream) {
  const float* z1 = (const float*)d_in[0];
  const float* z2 = (const float*)d_in[1];
  float* out = (float*)d_out;
  char* ws = (char*)d_ws;
  const size_t MB4 = (size_t)NROWS * DIM * 2;
  u16* z1q = (u16*)ws;                        // 4 MB (K1-scaled Q)
  u16* z1c = (u16*)(ws + MB4);                // 4 MB (unit, intra cols)
  u16* z2c = (u16*)(ws + 2 * MB4);            // 4 MB (unit, cross cols)
  float* pos = (float*)(ws + 3 * MB4);        // 64 KB
  float* lparts = (float*)(ws + 3 * MB4 + (size_t)NROWS * 4); // 1 MB

  hipMemsetAsync(d_out, 0, sizeof(float), stream);
  hipLaunchKernelGGL(nrm_kernel, dim3(NROWS / 4), dim3(256), 0, stream,
                     z1, z2, z1q, z1c, z2c, pos);
  hipLaunchKernelGGL(lse_kernel, dim3(1024), dim3(256), 0, stream,
                     z1q, z1c, z2c, lparts);
  hipLaunchKernelGGL(fin_kernel, dim3(32), dim3(256), 0, stream,
                     lparts, pos, out);
}